// Round 22
// baseline (482.431 us; speedup 1.0000x reference)
//
#include <hip/hip_runtime.h>
#include <hip/hip_bf16.h>

// FiLM + 2-layer preact resnet. N=65536, H=256, C=512.
// Round 22: cross-tile phase overlap. 512 blocks x 4 tiles of 32 rows each
// (persistent-style), LDS = 2 x 32KB buffers. Tile i computes out of
// buf[cur] (GEMM1 -> FiLM/r1 -> GEMM2/r2 -> GEMM3 -> fp32 epilogue, all
// reusing buf[cur], r18's proven patterns at 32-row scale) while tile i+1's
// cond is register-staged into buf[nxt] in two 16KB halves (issued under
// GEMM1 / written after B2; issued post-B2 / written after GEMM2) -> the
// previously fully-exposed 64KB HBM burst hides under a tile of compute.
// Existing barriers order all cross-buffer hazards (no new sync).

typedef __attribute__((ext_vector_type(8))) short bf16x8;   // 8 bf16 = 4 VGPR
typedef __attribute__((ext_vector_type(4))) float f32x4;    // MFMA C/D

typedef unsigned short ushort_t;
typedef unsigned int uint_t;

__device__ __forceinline__ ushort_t f2bfh(float f) {
  __hip_bfloat16 h = __float2bfloat16(f);            // RNE, hw cvt
  return *reinterpret_cast<ushort_t*>(&h);
}
__device__ __forceinline__ float bf2f(ushort_t s) {
  union { uint_t u; float f; } v; v.u = ((uint_t)s) << 16;
  return v.f;
}
__device__ __forceinline__ bf16x8 ldfrag(const ushort_t* p) {
  return *reinterpret_cast<const bf16x8*>(p);
}
__device__ __forceinline__ bf16x8 pack8(float4 a, float4 b) {
  union { bf16x8 v; __hip_bfloat162 h[4]; } u;       // v_cvt_pk_bf16_f32 x4
  u.h[0] = __float22bfloat162_rn(float2{a.x, a.y});
  u.h[1] = __float22bfloat162_rn(float2{a.z, a.w});
  u.h[2] = __float22bfloat162_rn(float2{b.x, b.y});
  u.h[3] = __float22bfloat162_rn(float2{b.z, b.w});
  return u.v;
}

// ---------------------------------------------------------------------------
// Pack weights (fp32 row-major [K][Ncols]) into bf16 MFMA-B fragment order:
//   p[((nt*KT + kt)*64 + lane)*8 + j] = W[kt*32 + (lane>>4)*8 + j][nt*16 + (lane&15)]
// ---------------------------------------------------------------------------
__global__ void pack_weights(const float* __restrict__ Wf,
                             const float* __restrict__ W1,
                             const float* __restrict__ W2,
                             ushort_t* __restrict__ p1,
                             ushort_t* __restrict__ pW1,
                             ushort_t* __restrict__ pW2) {
  int u = blockIdx.x * 256 + threadIdx.x;
  if (u < 32768) {
    int lane = u & 63, rest = u >> 6;
    int kt = rest & 15;
    int kb = kt * 32 + (lane >> 4) * 8;
    int col = (rest >> 4) * 16 + (lane & 15);
#pragma unroll
    for (int j = 0; j < 8; ++j)
      p1[(size_t)u * 8 + j] = f2bfh(Wf[(size_t)(kb + j) * 512 + col]);
  } else if (u < 40960) {
    int v = u - 32768;
    int lane = v & 63;
    int kt = (v >> 6) & 7;
    int kb = kt * 32 + (lane >> 4) * 8;
    int col = (v >> 9) * 16 + (lane & 15);
#pragma unroll
    for (int j = 0; j < 8; ++j)
      pW1[(size_t)v * 8 + j] = f2bfh(W1[(size_t)(kb + j) * 256 + col]);
  } else if (u < 49152) {
    int v = u - 40960;
    int lane = v & 63;
    int kt = (v >> 6) & 7;
    int kb = kt * 32 + (lane >> 4) * 8;
    int col = (v >> 9) * 16 + (lane & 15);
#pragma unroll
    for (int j = 0; j < 8; ++j)
      pW2[(size_t)v * 8 + j] = f2bfh(W2[(size_t)(kb + j) * 256 + col]);
  }
}

// ---------------------------------------------------------------------------
// Fused persistent-style: 512 blocks x 512 thr (8 waves); block b owns rows
// [b*128, b*128+128) as 4 tiles of 32. LDS: buf0=[0,32K), buf1=[32K,64K).
// Per tile (cur = tile&1):
//   buf[cur]: cond bf16 [32][512] (1KB/row) -> after B2: x bf16 [32][256] in
//   [0,16K), r1 bf16 [32][256] in [16K,32K), r2 over x, fp32 epi [32][256].
// XOR swizzle everywhere: byte ^= (row&15)<<4.
// GEMM1: wave w owns gb n-tiles {2w,2w+1} (gamma) + {16+2w,16+2w+1} (beta)
//   -> acc[2][4]. GEMM2/3: wave w owns H n-tiles {2w,2w+1} -> acc[2][2].
// ---------------------------------------------------------------------------
__global__ __launch_bounds__(512, 2)
void film_fused(const float* __restrict__ x, const float* __restrict__ cond,
                const float* __restrict__ b_film, const float* __restrict__ b1,
                const float* __restrict__ b2,
                const ushort_t* __restrict__ p1, const ushort_t* __restrict__ pW1,
                const ushort_t* __restrict__ pW2, float* __restrict__ out) {
  __shared__ __align__(16) char lds[65536];
  const int r0base = blockIdx.x * 128;
  const int t = threadIdx.x;
  const int w = t >> 6;
  const int l = t & 63;
  const int l15 = l & 15;
  const int lhi = l >> 4;

  // bias preloads (tile-invariant)
  float bgv[2], bbv[2], b1v[2], b2v[2];
#pragma unroll
  for (int tt = 0; tt < 2; ++tt) {
    int col = (2 * w + tt) * 16 + l15;
    bgv[tt] = b_film[col];
    bbv[tt] = b_film[256 + col];
    b1v[tt] = b1[col];
    b2v[tt] = b2[col];
  }

  // ---- prologue: stage cond tile 0 -> buf0 (monolithic, r18 pattern)
#pragma unroll
  for (int it = 0; it < 4; ++it) {
    int u = it * 512 + t;
    int row = u >> 6, k8 = u & 63;   // [32 rows][64 units of 8 cols]
    const float4* cs = reinterpret_cast<const float4*>(
        cond + (size_t)(r0base + row) * 512 + k8 * 8);
    float4 a = cs[0], b = cs[1];
    int byte = row * 1024 + k8 * 16;
    byte ^= ((row & 15) << 4);
    *reinterpret_cast<bf16x8*>(lds + byte) = pack8(a, b);
  }

#pragma unroll 1
  for (int tile = 0; tile < 4; ++tile) {
    char* bufc = lds + (tile & 1) * 32768;
    char* bufn = lds + ((tile & 1) ^ 1) * 32768;
    const int r0 = r0base + tile * 32;
    const int r0n = r0 + 32;          // next tile's rows (valid for tile<3)
    const bool more = (tile < 3);

    __syncthreads();   // B1: buf[cur] cond ready (prologue or prev staging)

    // issue next-tile cond HALF-0 loads (cols 0..255) -> covered by GEMM1
    float4 ch[4];
    if (more) {
#pragma unroll
      for (int i = 0; i < 2; ++i) {
        int g = i * 512 + t;
        int row = g >> 5, c8 = g & 31;   // [32 rows][32 units of 8 cols]
        const float4* cs = reinterpret_cast<const float4*>(
            cond + (size_t)(r0n + row) * 512 + c8 * 8);
        ch[i * 2] = cs[0];
        ch[i * 2 + 1] = cs[1];
      }
    }
    // GEMM1 B preload kt=0
    bf16x8 bb[2][4];
#pragma unroll
    for (int j = 0; j < 4; ++j) {
      int nt = (j < 2) ? (2 * w + j) : (16 + 2 * w + (j - 2));
      bb[0][j] = ldfrag(p1 + ((size_t)(nt * 16 + 0) * 64 + l) * 8);
    }

    // ---- GEMM1: acc[2][4] over 16 kt, 2-slot B pipeline (r18 loop @32 rows)
    f32x4 acc[2][4];
#pragma unroll
    for (int m = 0; m < 2; ++m)
#pragma unroll
      for (int n = 0; n < 4; ++n) acc[m][n] = (f32x4){0.f, 0.f, 0.f, 0.f};

#pragma unroll
    for (int kt = 0; kt < 16; ++kt) {
      const int cur = kt & 1;
      if (kt < 15) {
#pragma unroll
        for (int j = 0; j < 4; ++j) {
          int nt = (j < 2) ? (2 * w + j) : (16 + 2 * w + (j - 2));
          bb[cur ^ 1][j] = ldfrag(p1 + ((size_t)(nt * 16 + kt + 1) * 64 + l) * 8);
        }
      }
      bf16x8 afr[2];
#pragma unroll
      for (int m = 0; m < 2; ++m) {
        int row = m * 16 + l15;
        int byte = row * 1024 + kt * 64 + lhi * 16;
        byte ^= ((row & 15) << 4);
        afr[m] = *reinterpret_cast<const bf16x8*>(bufc + byte);
      }
      __builtin_amdgcn_s_setprio(1);
#pragma unroll
      for (int j = 0; j < 4; ++j)
#pragma unroll
        for (int m = 0; m < 2; ++m)
          acc[m][j] = __builtin_amdgcn_mfma_f32_16x16x32_bf16(afr[m], bb[cur][j], acc[m][j], 0, 0, 0);
      __builtin_amdgcn_s_setprio(0);
    }

    // issue x loads for THIS tile (drain at B2 is the only exposure)
    float4 xl[4];
#pragma unroll
    for (int i = 0; i < 2; ++i) {
      int g = i * 512 + t;
      int row = g >> 5, c8 = g & 31;
      const float4* xs = reinterpret_cast<const float4*>(
          x + (size_t)(r0 + row) * 256 + c8 * 8);
      xl[i * 2] = xs[0];
      xl[i * 2 + 1] = xs[1];
    }
    __syncthreads();   // B2: all cond reads done -> buf[cur] reusable

    // write cond_next half0 -> buf[nxt] cols [0,256)
    if (more) {
#pragma unroll
      for (int i = 0; i < 2; ++i) {
        int g = i * 512 + t;
        int row = g >> 5, c8 = g & 31;
        int byte = row * 1024 + c8 * 16;        // half 0: bytes [0,512)/row
        byte ^= ((row & 15) << 4);
        *reinterpret_cast<bf16x8*>(bufn + byte) = pack8(ch[i * 2], ch[i * 2 + 1]);
      }
    }
    // write x bf16 -> buf[cur][0,16K)
#pragma unroll
    for (int i = 0; i < 2; ++i) {
      int g = i * 512 + t;
      int row = g >> 5, c8 = g & 31;
      int byte = row * 512 + c8 * 16;
      byte ^= ((row & 15) << 4);
      *reinterpret_cast<bf16x8*>(bufc + byte) = pack8(xl[i * 2], xl[i * 2 + 1]);
    }
    // issue next-tile cond HALF-1 loads (cols 256..511) -> covered to GEMM2 end
    if (more) {
#pragma unroll
      for (int i = 0; i < 2; ++i) {
        int g = i * 512 + t;
        int row = g >> 5, c8 = g & 31;
        const float4* cs = reinterpret_cast<const float4*>(
            cond + (size_t)(r0n + row) * 512 + 256 + c8 * 8);
        ch[i * 2] = cs[0];
        ch[i * 2 + 1] = cs[1];
      }
    }
    __syncthreads();   // B3: x staged

    // ---- FiLM: r1 = relu((accg+bg)*x + (accb+bb)) -> buf[cur][16K,32K)
#pragma unroll
    for (int m = 0; m < 2; ++m) {
#pragma unroll
      for (int tt = 0; tt < 2; ++tt) {
        int col = (2 * w + tt) * 16 + l15;
#pragma unroll
        for (int reg = 0; reg < 4; ++reg) {
          int row = m * 16 + lhi * 4 + reg;
          int byte = row * 512 + col * 2;
          byte ^= ((row & 15) << 4);
          float xv = bf2f(*reinterpret_cast<const ushort_t*>(bufc + byte));
          float hv = fmaxf((acc[m][tt][reg] + bgv[tt]) * xv +
                               (acc[m][2 + tt][reg] + bbv[tt]), 0.f);
          *reinterpret_cast<ushort_t*>(bufc + 16384 + byte) = f2bfh(hv);
        }
      }
    }
    // GEMM2 B preload
    bf16x8 bb2[2][2];
#pragma unroll
    for (int tt = 0; tt < 2; ++tt)
      bb2[0][tt] = ldfrag(pW1 + ((size_t)((2 * w + tt) * 8 + 0) * 64 + l) * 8);
    __syncthreads();   // B4: r1 ready

    // ---- GEMM2: acc2 = r1 @ W1 (K=256, 8 kt)
    f32x4 acc2[2][2];
#pragma unroll
    for (int m = 0; m < 2; ++m)
#pragma unroll
      for (int n = 0; n < 2; ++n) acc2[m][n] = (f32x4){0.f, 0.f, 0.f, 0.f};

#pragma unroll
    for (int kt = 0; kt < 8; ++kt) {
      const int cur = kt & 1;
      if (kt < 7) {
#pragma unroll
        for (int tt = 0; tt < 2; ++tt)
          bb2[cur ^ 1][tt] = ldfrag(pW1 + ((size_t)((2 * w + tt) * 8 + kt + 1) * 64 + l) * 8);
      }
      bf16x8 afr[2];
#pragma unroll
      for (int m = 0; m < 2; ++m) {
        int row = m * 16 + l15;
        int byte = row * 512 + kt * 64 + lhi * 16;
        byte ^= ((row & 15) << 4);
        afr[m] = *reinterpret_cast<const bf16x8*>(bufc + 16384 + byte);
      }
      __builtin_amdgcn_s_setprio(1);
#pragma unroll
      for (int tt = 0; tt < 2; ++tt)
#pragma unroll
        for (int m = 0; m < 2; ++m)
          acc2[m][tt] = __builtin_amdgcn_mfma_f32_16x16x32_bf16(afr[m], bb2[cur][tt], acc2[m][tt], 0, 0, 0);
      __builtin_amdgcn_s_setprio(0);
    }

    // write cond_next half1 -> buf[nxt] cols [256,512)
    if (more) {
#pragma unroll
      for (int i = 0; i < 2; ++i) {
        int g = i * 512 + t;
        int row = g >> 5, c8 = g & 31;
        int byte = row * 1024 + 512 + c8 * 16;  // half 1: bytes [512,1024)/row
        byte ^= ((row & 15) << 4);
        *reinterpret_cast<bf16x8*>(bufn + byte) = pack8(ch[i * 2], ch[i * 2 + 1]);
      }
    }
    // r2 = relu(acc2+b1) -> buf[cur][0,16K) (x dead; disjoint from r1 reads)
#pragma unroll
    for (int tt = 0; tt < 2; ++tt) {
      int col = (2 * w + tt) * 16 + l15;
#pragma unroll
      for (int m = 0; m < 2; ++m)
#pragma unroll
        for (int reg = 0; reg < 4; ++reg) {
          int row = m * 16 + lhi * 4 + reg;
          int byte = row * 512 + col * 2;
          byte ^= ((row & 15) << 4);
          *reinterpret_cast<ushort_t*>(bufc + byte) = f2bfh(fmaxf(acc2[m][tt][reg] + b1v[tt], 0.f));
        }
    }
    // GEMM3 B preload
    bf16x8 bb3[2][2];
#pragma unroll
    for (int tt = 0; tt < 2; ++tt)
      bb3[0][tt] = ldfrag(pW2 + ((size_t)((2 * w + tt) * 8 + 0) * 64 + l) * 8);
    __syncthreads();   // B5: r2 ready

    // ---- GEMM3: acc3 = r2 @ W2 (K=256, 8 kt)
    f32x4 acc3[2][2];
#pragma unroll
    for (int m = 0; m < 2; ++m)
#pragma unroll
      for (int n = 0; n < 2; ++n) acc3[m][n] = (f32x4){0.f, 0.f, 0.f, 0.f};

#pragma unroll
    for (int kt = 0; kt < 8; ++kt) {
      const int cur = kt & 1;
      if (kt < 7) {
#pragma unroll
        for (int tt = 0; tt < 2; ++tt)
          bb3[cur ^ 1][tt] = ldfrag(pW2 + ((size_t)((2 * w + tt) * 8 + kt + 1) * 64 + l) * 8);
      }
      bf16x8 afr[2];
#pragma unroll
      for (int m = 0; m < 2; ++m) {
        int row = m * 16 + l15;
        int byte = row * 512 + kt * 64 + lhi * 16;
        byte ^= ((row & 15) << 4);
        afr[m] = *reinterpret_cast<const bf16x8*>(bufc + byte);
      }
      __builtin_amdgcn_s_setprio(1);
#pragma unroll
      for (int tt = 0; tt < 2; ++tt)
#pragma unroll
        for (int m = 0; m < 2; ++m)
          acc3[m][tt] = __builtin_amdgcn_mfma_f32_16x16x32_bf16(afr[m], bb3[cur][tt], acc3[m][tt], 0, 0, 0);
      __builtin_amdgcn_s_setprio(0);
    }
    __syncthreads();   // B6: r2 reads done -> buf[cur] free

    // ---- epilogue: fp32 [32][256] in buf[cur], +b2 at dump; coalesced
    // nontemporal stores with L3-warm x residual.
#pragma unroll
    for (int tt = 0; tt < 2; ++tt) {
      int col = (2 * w + tt) * 16 + l15;
#pragma unroll
      for (int m = 0; m < 2; ++m)
#pragma unroll
        for (int reg = 0; reg < 4; ++reg) {
          int row = m * 16 + lhi * 4 + reg;
          int byte = row * 1024 + col * 4;
          byte ^= ((row & 15) << 4);
          *reinterpret_cast<float*>(bufc + byte) = acc3[m][tt][reg] + b2v[tt];
        }
    }
    __syncthreads();   // B7: tile ready
#pragma unroll
    for (int i = 0; i < 4; ++i) {
      int u = i * 512 + t;
      int row = u >> 6, c4 = u & 63;   // [32 rows][64 units of 4 cols]
      int byte = row * 1024 + c4 * 16;
      byte ^= ((row & 15) << 4);
      f32x4 v = *reinterpret_cast<const f32x4*>(bufc + byte);
      const float4 xres = *reinterpret_cast<const float4*>(
          x + (size_t)(r0 + row) * 256 + c4 * 4);
      v.x += xres.x; v.y += xres.y; v.z += xres.z; v.w += xres.w;
      f32x4* op = reinterpret_cast<f32x4*>(out + (size_t)(r0 + row) * 256 + c4 * 4);
      __builtin_nontemporal_store(v, op);
    }
    // next tile's B1 separates these epilogue LDS reads from any future
    // writes into buf[cur] (which first happen after next tile's B2).
  }
}

extern "C" void kernel_launch(void* const* d_in, const int* in_sizes, int n_in,
                              void* d_out, int out_size, void* d_ws, size_t ws_size,
                              hipStream_t stream) {
  const float* x      = (const float*)d_in[0];
  const float* cond   = (const float*)d_in[1];
  const float* W_film = (const float*)d_in[2];
  const float* b_film = (const float*)d_in[3];
  const float* W1     = (const float*)d_in[4];
  const float* b1     = (const float*)d_in[5];
  const float* W2     = (const float*)d_in[6];
  const float* b2     = (const float*)d_in[7];
  float* out = (float*)d_out;

  ushort_t* p1  = (ushort_t*)d_ws;       // 512KB
  ushort_t* pW1 = p1 + 262144;           // 128KB
  ushort_t* pW2 = pW1 + 65536;           // 128KB

  hipLaunchKernelGGL(pack_weights, dim3(192), dim3(256), 0, stream,
                     W_film, W1, W2, p1, pW1, pW2);
  hipLaunchKernelGGL(film_fused, dim3(512), dim3(512), 0, stream,
                     x, cond, b_film, b1, b2, p1, pW1, pW2, out);
}

// Round 23
// 112.052 us; speedup vs baseline: 4.3054x; 4.3054x over previous
//
#include <hip/hip_runtime.h>
#include <hip/hip_bf16.h>

// FiLM + 2-layer preact resnet. N=65536, H=256, C=512.
// Round 23: r22's cross-tile overlap, register-disciplined. 512 blocks x
// 4 tiles of 32 rows, LDS 2x32KB. Fixes vs r22 (which spilled at the 128
// box): (1) ALL GEMM K-loops rolled (unroll 1) with named 2-slot pipeline
// regs (r21's proven pattern, VGPR 36 there); (2) next-tile cond staged in
// FOUR 8-reg quarters (ch[2] float4), anchored Q0:B1->B2, Q1:B2->B3,
// Q2:B3->B4, Q3:B4->B5. All writes to buf[nxt] land before next tile's B1.

typedef __attribute__((ext_vector_type(8))) short bf16x8;   // 8 bf16 = 4 VGPR
typedef __attribute__((ext_vector_type(4))) float f32x4;    // MFMA C/D

typedef unsigned short ushort_t;
typedef unsigned int uint_t;

__device__ __forceinline__ ushort_t f2bfh(float f) {
  __hip_bfloat16 h = __float2bfloat16(f);            // RNE, hw cvt
  return *reinterpret_cast<ushort_t*>(&h);
}
__device__ __forceinline__ float bf2f(ushort_t s) {
  union { uint_t u; float f; } v; v.u = ((uint_t)s) << 16;
  return v.f;
}
__device__ __forceinline__ bf16x8 ldfrag(const ushort_t* p) {
  return *reinterpret_cast<const bf16x8*>(p);
}
__device__ __forceinline__ bf16x8 pack8(float4 a, float4 b) {
  union { bf16x8 v; __hip_bfloat162 h[4]; } u;       // v_cvt_pk_bf16_f32 x4
  u.h[0] = __float22bfloat162_rn(float2{a.x, a.y});
  u.h[1] = __float22bfloat162_rn(float2{a.z, a.w});
  u.h[2] = __float22bfloat162_rn(float2{b.x, b.y});
  u.h[3] = __float22bfloat162_rn(float2{b.z, b.w});
  return u.v;
}

// ---------------------------------------------------------------------------
// Pack weights (fp32 row-major [K][Ncols]) into bf16 MFMA-B fragment order:
//   p[((nt*KT + kt)*64 + lane)*8 + j] = W[kt*32 + (lane>>4)*8 + j][nt*16 + (lane&15)]
// ---------------------------------------------------------------------------
__global__ void pack_weights(const float* __restrict__ Wf,
                             const float* __restrict__ W1,
                             const float* __restrict__ W2,
                             ushort_t* __restrict__ p1,
                             ushort_t* __restrict__ pW1,
                             ushort_t* __restrict__ pW2) {
  int u = blockIdx.x * 256 + threadIdx.x;
  if (u < 32768) {
    int lane = u & 63, rest = u >> 6;
    int kt = rest & 15;
    int kb = kt * 32 + (lane >> 4) * 8;
    int col = (rest >> 4) * 16 + (lane & 15);
#pragma unroll
    for (int j = 0; j < 8; ++j)
      p1[(size_t)u * 8 + j] = f2bfh(Wf[(size_t)(kb + j) * 512 + col]);
  } else if (u < 40960) {
    int v = u - 32768;
    int lane = v & 63;
    int kt = (v >> 6) & 7;
    int kb = kt * 32 + (lane >> 4) * 8;
    int col = (v >> 9) * 16 + (lane & 15);
#pragma unroll
    for (int j = 0; j < 8; ++j)
      pW1[(size_t)v * 8 + j] = f2bfh(W1[(size_t)(kb + j) * 256 + col]);
  } else if (u < 49152) {
    int v = u - 40960;
    int lane = v & 63;
    int kt = (v >> 6) & 7;
    int kb = kt * 32 + (lane >> 4) * 8;
    int col = (v >> 9) * 16 + (lane & 15);
#pragma unroll
    for (int j = 0; j < 8; ++j)
      pW2[(size_t)v * 8 + j] = f2bfh(W2[(size_t)(kb + j) * 256 + col]);
  }
}

// ---------------------------------------------------------------------------
// Fused persistent-style: 512 blocks x 512 thr (8 waves); block b owns rows
// [b*128,+128) as 4 tiles of 32. LDS: buf0=[0,32K), buf1=[32K,64K).
// Per tile (bufc = buf[tile&1]): cond bf16 [32][512] (1KB/row) -> after B2:
// x bf16 [32][256] in [0,16K), r1 in [16K,32K), r2 over x, fp32 epi [32][256].
// XOR swz: byte ^= (row&15)<<4.
// GEMM1: wave w owns gb n-tiles {2w,2w+1} (gamma) + {16+2w,16+2w+1} (beta)
//   -> acc[2][4]. GEMM2/3: wave w owns H n-tiles {2w,2w+1} -> acc[2][2].
// Next-tile cond quarter q (cols q*128..+128): thread t owns 8 floats at
//   row=t>>4, c8=t&15; write byte = row*1024 + q*256 + c8*16 (^swz) in bufn.
// ---------------------------------------------------------------------------
__global__ __launch_bounds__(512, 2)
void film_fused(const float* __restrict__ x, const float* __restrict__ cond,
                const float* __restrict__ b_film, const float* __restrict__ b1,
                const float* __restrict__ b2,
                const ushort_t* __restrict__ p1, const ushort_t* __restrict__ pW1,
                const ushort_t* __restrict__ pW2, float* __restrict__ out) {
  __shared__ __align__(16) char lds[65536];
  const int r0base = blockIdx.x * 128;
  const int t = threadIdx.x;
  const int w = t >> 6;
  const int l = t & 63;
  const int l15 = l & 15;
  const int lhi = l >> 4;

  // bias preloads (tile-invariant)
  float bgv[2], bbv[2], b1v[2], b2v[2];
#pragma unroll
  for (int tt = 0; tt < 2; ++tt) {
    int col = (2 * w + tt) * 16 + l15;
    bgv[tt] = b_film[col];
    bbv[tt] = b_film[256 + col];
    b1v[tt] = b1[col];
    b2v[tt] = b2[col];
  }
  // quarter-staging geometry (constant per thread)
  const int qrow = t >> 4;          // 0..31
  const int qc8 = t & 15;           // 8-col unit within a 128-col quarter

  // ---- prologue: stage cond tile 0 -> buf0
#pragma unroll
  for (int it = 0; it < 4; ++it) {
    int u = it * 512 + t;
    int row = u >> 6, k8 = u & 63;
    const float4* cs = reinterpret_cast<const float4*>(
        cond + (size_t)(r0base + row) * 512 + k8 * 8);
    float4 a = cs[0], b = cs[1];
    int byte = row * 1024 + k8 * 16;
    byte ^= ((row & 15) << 4);
    *reinterpret_cast<bf16x8*>(lds + byte) = pack8(a, b);
  }

#pragma unroll 1
  for (int tile = 0; tile < 4; ++tile) {
    char* bufc = lds + (tile & 1) * 32768;
    char* bufn = lds + ((tile & 1) ^ 1) * 32768;
    const int r0 = r0base + tile * 32;
    const int r0n = r0 + 32;
    const bool more = (tile < 3);

    __syncthreads();   // B1: buf[cur] cond ready; prev tile fully done

    // issue next-cond Q0 loads (covered by GEMM1)
    float4 ch[2];
    if (more) {
      const float4* cs = reinterpret_cast<const float4*>(
          cond + (size_t)(r0n + qrow) * 512 + 0 * 128 + qc8 * 8);
      ch[0] = cs[0];
      ch[1] = cs[1];
    }
    // GEMM1 B preload kt=0 (named pipeline regs)
    bf16x8 bcur[4], bnx[4];
#pragma unroll
    for (int j = 0; j < 4; ++j) {
      int nt = (j < 2) ? (2 * w + j) : (16 + 2 * w + (j - 2));
      bcur[j] = ldfrag(p1 + ((size_t)(nt * 16 + 0) * 64 + l) * 8);
    }

    // ---- GEMM1: acc[2][4] over 16 kt, ROLLED kp loop (2 kt each)
    f32x4 acc[2][4];
#pragma unroll
    for (int m = 0; m < 2; ++m)
#pragma unroll
      for (int n = 0; n < 4; ++n) acc[m][n] = (f32x4){0.f, 0.f, 0.f, 0.f};

#pragma unroll 1
    for (int kp = 0; kp < 8; ++kp) {
      const int kt0 = kp * 2;
#pragma unroll
      for (int j = 0; j < 4; ++j) {
        int nt = (j < 2) ? (2 * w + j) : (16 + 2 * w + (j - 2));
        bnx[j] = ldfrag(p1 + ((size_t)(nt * 16 + kt0 + 1) * 64 + l) * 8);
      }
      {
        bf16x8 afr[2];
#pragma unroll
        for (int m = 0; m < 2; ++m) {
          int row = m * 16 + l15;
          int byte = row * 1024 + kt0 * 64 + lhi * 16;
          byte ^= ((row & 15) << 4);
          afr[m] = *reinterpret_cast<const bf16x8*>(bufc + byte);
        }
        __builtin_amdgcn_s_setprio(1);
#pragma unroll
        for (int j = 0; j < 4; ++j)
#pragma unroll
          for (int m = 0; m < 2; ++m)
            acc[m][j] = __builtin_amdgcn_mfma_f32_16x16x32_bf16(afr[m], bcur[j], acc[m][j], 0, 0, 0);
        __builtin_amdgcn_s_setprio(0);
      }
      if (kt0 + 2 < 16) {
#pragma unroll
        for (int j = 0; j < 4; ++j) {
          int nt = (j < 2) ? (2 * w + j) : (16 + 2 * w + (j - 2));
          bcur[j] = ldfrag(p1 + ((size_t)(nt * 16 + kt0 + 2) * 64 + l) * 8);
        }
      }
      {
        bf16x8 afr[2];
#pragma unroll
        for (int m = 0; m < 2; ++m) {
          int row = m * 16 + l15;
          int byte = row * 1024 + (kt0 + 1) * 64 + lhi * 16;
          byte ^= ((row & 15) << 4);
          afr[m] = *reinterpret_cast<const bf16x8*>(bufc + byte);
        }
        __builtin_amdgcn_s_setprio(1);
#pragma unroll
        for (int j = 0; j < 4; ++j)
#pragma unroll
          for (int m = 0; m < 2; ++m)
            acc[m][j] = __builtin_amdgcn_mfma_f32_16x16x32_bf16(afr[m], bnx[j], acc[m][j], 0, 0, 0);
        __builtin_amdgcn_s_setprio(0);
      }
    }

    // issue x loads for THIS tile
    float4 xl[4];
#pragma unroll
    for (int i = 0; i < 2; ++i) {
      int g = i * 512 + t;
      int row = g >> 5, c8 = g & 31;
      const float4* xs = reinterpret_cast<const float4*>(
          x + (size_t)(r0 + row) * 256 + c8 * 8);
      xl[i * 2] = xs[0];
      xl[i * 2 + 1] = xs[1];
    }
    __syncthreads();   // B2: all cond reads done -> buf[cur] reusable

    // write Q0 -> bufn; issue Q1
    if (more) {
      int byte = qrow * 1024 + 0 * 256 + qc8 * 16;
      byte ^= ((qrow & 15) << 4);
      *reinterpret_cast<bf16x8*>(bufn + byte) = pack8(ch[0], ch[1]);
      const float4* cs = reinterpret_cast<const float4*>(
          cond + (size_t)(r0n + qrow) * 512 + 1 * 128 + qc8 * 8);
      ch[0] = cs[0];
      ch[1] = cs[1];
    }
    // write x bf16 -> bufc[0,16K)
#pragma unroll
    for (int i = 0; i < 2; ++i) {
      int g = i * 512 + t;
      int row = g >> 5, c8 = g & 31;
      int byte = row * 512 + c8 * 16;
      byte ^= ((row & 15) << 4);
      *reinterpret_cast<bf16x8*>(bufc + byte) = pack8(xl[i * 2], xl[i * 2 + 1]);
    }
    __syncthreads();   // B3: x staged

    // write Q1 -> bufn; issue Q2
    if (more) {
      int byte = qrow * 1024 + 1 * 256 + qc8 * 16;
      byte ^= ((qrow & 15) << 4);
      *reinterpret_cast<bf16x8*>(bufn + byte) = pack8(ch[0], ch[1]);
      const float4* cs = reinterpret_cast<const float4*>(
          cond + (size_t)(r0n + qrow) * 512 + 2 * 128 + qc8 * 8);
      ch[0] = cs[0];
      ch[1] = cs[1];
    }
    // ---- FiLM: r1 = relu((accg+bg)*x + (accb+bb)) -> bufc[16K,32K)
#pragma unroll
    for (int m = 0; m < 2; ++m) {
#pragma unroll
      for (int tt = 0; tt < 2; ++tt) {
        int col = (2 * w + tt) * 16 + l15;
#pragma unroll
        for (int reg = 0; reg < 4; ++reg) {
          int row = m * 16 + lhi * 4 + reg;
          int byte = row * 512 + col * 2;
          byte ^= ((row & 15) << 4);
          float xv = bf2f(*reinterpret_cast<const ushort_t*>(bufc + byte));
          float hv = fmaxf((acc[m][tt][reg] + bgv[tt]) * xv +
                               (acc[m][2 + tt][reg] + bbv[tt]), 0.f);
          *reinterpret_cast<ushort_t*>(bufc + 16384 + byte) = f2bfh(hv);
        }
      }
    }
    // GEMM2 B preload (named)
    bf16x8 c2a = ldfrag(pW1 + ((size_t)((2 * w + 0) * 8 + 0) * 64 + l) * 8);
    bf16x8 c2b = ldfrag(pW1 + ((size_t)((2 * w + 1) * 8 + 0) * 64 + l) * 8);
    __syncthreads();   // B4: r1 ready

    // write Q2 -> bufn; issue Q3
    if (more) {
      int byte = qrow * 1024 + 2 * 256 + qc8 * 16;
      byte ^= ((qrow & 15) << 4);
      *reinterpret_cast<bf16x8*>(bufn + byte) = pack8(ch[0], ch[1]);
      const float4* cs = reinterpret_cast<const float4*>(
          cond + (size_t)(r0n + qrow) * 512 + 3 * 128 + qc8 * 8);
      ch[0] = cs[0];
      ch[1] = cs[1];
    }
    // ---- GEMM2: acc2 = r1 @ W1 (K=256), ROLLED kp loop
    f32x4 acc2[2][2];
#pragma unroll
    for (int m = 0; m < 2; ++m)
#pragma unroll
      for (int n = 0; n < 2; ++n) acc2[m][n] = (f32x4){0.f, 0.f, 0.f, 0.f};

#pragma unroll 1
    for (int kp = 0; kp < 4; ++kp) {
      const int kt0 = kp * 2;
      bf16x8 n2a = ldfrag(pW1 + ((size_t)((2 * w + 0) * 8 + kt0 + 1) * 64 + l) * 8);
      bf16x8 n2b = ldfrag(pW1 + ((size_t)((2 * w + 1) * 8 + kt0 + 1) * 64 + l) * 8);
      {
        bf16x8 afr[2];
#pragma unroll
        for (int m = 0; m < 2; ++m) {
          int row = m * 16 + l15;
          int byte = row * 512 + kt0 * 64 + lhi * 16;
          byte ^= ((row & 15) << 4);
          afr[m] = *reinterpret_cast<const bf16x8*>(bufc + 16384 + byte);
        }
        __builtin_amdgcn_s_setprio(1);
#pragma unroll
        for (int m = 0; m < 2; ++m) {
          acc2[m][0] = __builtin_amdgcn_mfma_f32_16x16x32_bf16(afr[m], c2a, acc2[m][0], 0, 0, 0);
          acc2[m][1] = __builtin_amdgcn_mfma_f32_16x16x32_bf16(afr[m], c2b, acc2[m][1], 0, 0, 0);
        }
        __builtin_amdgcn_s_setprio(0);
      }
      if (kt0 + 2 < 8) {
        c2a = ldfrag(pW1 + ((size_t)((2 * w + 0) * 8 + kt0 + 2) * 64 + l) * 8);
        c2b = ldfrag(pW1 + ((size_t)((2 * w + 1) * 8 + kt0 + 2) * 64 + l) * 8);
      }
      {
        bf16x8 afr[2];
#pragma unroll
        for (int m = 0; m < 2; ++m) {
          int row = m * 16 + l15;
          int byte = row * 512 + (kt0 + 1) * 64 + lhi * 16;
          byte ^= ((row & 15) << 4);
          afr[m] = *reinterpret_cast<const bf16x8*>(bufc + 16384 + byte);
        }
        __builtin_amdgcn_s_setprio(1);
#pragma unroll
        for (int m = 0; m < 2; ++m) {
          acc2[m][0] = __builtin_amdgcn_mfma_f32_16x16x32_bf16(afr[m], n2a, acc2[m][0], 0, 0, 0);
          acc2[m][1] = __builtin_amdgcn_mfma_f32_16x16x32_bf16(afr[m], n2b, acc2[m][1], 0, 0, 0);
        }
        __builtin_amdgcn_s_setprio(0);
      }
    }

    // r2 = relu(acc2+b1) -> bufc[0,16K) (x dead after B4; disjoint from r1)
#pragma unroll
    for (int tt = 0; tt < 2; ++tt) {
      int col = (2 * w + tt) * 16 + l15;
#pragma unroll
      for (int m = 0; m < 2; ++m)
#pragma unroll
        for (int reg = 0; reg < 4; ++reg) {
          int row = m * 16 + lhi * 4 + reg;
          int byte = row * 512 + col * 2;
          byte ^= ((row & 15) << 4);
          *reinterpret_cast<ushort_t*>(bufc + byte) = f2bfh(fmaxf(acc2[m][tt][reg] + b1v[tt], 0.f));
        }
    }
    // GEMM3 B preload (named)
    bf16x8 c3a = ldfrag(pW2 + ((size_t)((2 * w + 0) * 8 + 0) * 64 + l) * 8);
    bf16x8 c3b = ldfrag(pW2 + ((size_t)((2 * w + 1) * 8 + 0) * 64 + l) * 8);
    __syncthreads();   // B5: r2 ready

    // write Q3 -> bufn (last quarter; lands before next tile's B1)
    if (more) {
      int byte = qrow * 1024 + 3 * 256 + qc8 * 16;
      byte ^= ((qrow & 15) << 4);
      *reinterpret_cast<bf16x8*>(bufn + byte) = pack8(ch[0], ch[1]);
    }
    // ---- GEMM3: acc3 = r2 @ W2 (K=256), ROLLED kp loop
    f32x4 acc3[2][2];
#pragma unroll
    for (int m = 0; m < 2; ++m)
#pragma unroll
      for (int n = 0; n < 2; ++n) acc3[m][n] = (f32x4){0.f, 0.f, 0.f, 0.f};

#pragma unroll 1
    for (int kp = 0; kp < 4; ++kp) {
      const int kt0 = kp * 2;
      bf16x8 n3a = ldfrag(pW2 + ((size_t)((2 * w + 0) * 8 + kt0 + 1) * 64 + l) * 8);
      bf16x8 n3b = ldfrag(pW2 + ((size_t)((2 * w + 1) * 8 + kt0 + 1) * 64 + l) * 8);
      {
        bf16x8 afr[2];
#pragma unroll
        for (int m = 0; m < 2; ++m) {
          int row = m * 16 + l15;
          int byte = row * 512 + kt0 * 64 + lhi * 16;
          byte ^= ((row & 15) << 4);
          afr[m] = *reinterpret_cast<const bf16x8*>(bufc + byte);
        }
        __builtin_amdgcn_s_setprio(1);
#pragma unroll
        for (int m = 0; m < 2; ++m) {
          acc3[m][0] = __builtin_amdgcn_mfma_f32_16x16x32_bf16(afr[m], c3a, acc3[m][0], 0, 0, 0);
          acc3[m][1] = __builtin_amdgcn_mfma_f32_16x16x32_bf16(afr[m], c3b, acc3[m][1], 0, 0, 0);
        }
        __builtin_amdgcn_s_setprio(0);
      }
      if (kt0 + 2 < 8) {
        c3a = ldfrag(pW2 + ((size_t)((2 * w + 0) * 8 + kt0 + 2) * 64 + l) * 8);
        c3b = ldfrag(pW2 + ((size_t)((2 * w + 1) * 8 + kt0 + 2) * 64 + l) * 8);
      }
      {
        bf16x8 afr[2];
#pragma unroll
        for (int m = 0; m < 2; ++m) {
          int row = m * 16 + l15;
          int byte = row * 512 + (kt0 + 1) * 64 + lhi * 16;
          byte ^= ((row & 15) << 4);
          afr[m] = *reinterpret_cast<const bf16x8*>(bufc + byte);
        }
        __builtin_amdgcn_s_setprio(1);
#pragma unroll
        for (int m = 0; m < 2; ++m) {
          acc3[m][0] = __builtin_amdgcn_mfma_f32_16x16x32_bf16(afr[m], n3a, acc3[m][0], 0, 0, 0);
          acc3[m][1] = __builtin_amdgcn_mfma_f32_16x16x32_bf16(afr[m], n3b, acc3[m][1], 0, 0, 0);
        }
        __builtin_amdgcn_s_setprio(0);
      }
    }
    __syncthreads();   // B6: r2 reads done -> buf[cur] free

    // ---- epilogue: fp32 [32][256] in bufc; +b2 at dump; coalesced
    // nontemporal stores with L3-warm x residual.
#pragma unroll
    for (int tt = 0; tt < 2; ++tt) {
      int col = (2 * w + tt) * 16 + l15;
#pragma unroll
      for (int m = 0; m < 2; ++m)
#pragma unroll
        for (int reg = 0; reg < 4; ++reg) {
          int row = m * 16 + lhi * 4 + reg;
          int byte = row * 1024 + col * 4;
          byte ^= ((row & 15) << 4);
          *reinterpret_cast<float*>(bufc + byte) = acc3[m][tt][reg] + b2v[tt];
        }
    }
    __syncthreads();   // B7: tile ready
#pragma unroll
    for (int i = 0; i < 4; ++i) {
      int u = i * 512 + t;
      int row = u >> 6, c4 = u & 63;
      int byte = row * 1024 + c4 * 16;
      byte ^= ((row & 15) << 4);
      f32x4 v = *reinterpret_cast<const f32x4*>(bufc + byte);
      const float4 xres = *reinterpret_cast<const float4*>(
          x + (size_t)(r0 + row) * 256 + c4 * 4);
      v.x += xres.x; v.y += xres.y; v.z += xres.z; v.w += xres.w;
      f32x4* op = reinterpret_cast<f32x4*>(out + (size_t)(r0 + row) * 256 + c4 * 4);
      __builtin_nontemporal_store(v, op);
    }
    // next tile's B1 orders these epilogue reads before any bufc overwrite.
  }
}

extern "C" void kernel_launch(void* const* d_in, const int* in_sizes, int n_in,
                              void* d_out, int out_size, void* d_ws, size_t ws_size,
                              hipStream_t stream) {
  const float* x      = (const float*)d_in[0];
  const float* cond   = (const float*)d_in[1];
  const float* W_film = (const float*)d_in[2];
  const float* b_film = (const float*)d_in[3];
  const float* W1     = (const float*)d_in[4];
  const float* b1     = (const float*)d_in[5];
  const float* W2     = (const float*)d_in[6];
  const float* b2     = (const float*)d_in[7];
  float* out = (float*)d_out;

  ushort_t* p1  = (ushort_t*)d_ws;       // 512KB
  ushort_t* pW1 = p1 + 262144;           // 128KB
  ushort_t* pW2 = pW1 + 65536;           // 128KB

  hipLaunchKernelGGL(pack_weights, dim3(192), dim3(256), 0, stream,
                     W_film, W1, W2, p1, pW1, pW2);
  hipLaunchKernelGGL(film_fused, dim3(512), dim3(512), 0, stream,
                     x, cond, b_film, b1, b2, p1, pW1, pW2, out);
}

// Round 24
// 108.452 us; speedup vs baseline: 4.4483x; 1.0332x over previous
//
#include <hip/hip_runtime.h>
#include <hip/hip_bf16.h>

// FiLM + 2-layer preact resnet. N=65536, H=256, C=512.
// Round 24: r18 (best, 98.3us) + two cheap evidence-backed tweaks:
//  (1) s_setprio REMOVED everywhere -- m190 measured setprio negative on
//      barrier-lockstep GEMM structures (all our waves are phase-locked);
//  (2) XCD-aware bijective blockIdx swizzle (nwg=1024 % 8 == 0) so
//      consecutive-row blocks share an XCD L2 for the 768KB weight stream.
// Everything else identical to r18 (gamma/beta through LDS, in-place r1/r2,
// fp32-LDS epilogue, L3-warm x residual).

typedef __attribute__((ext_vector_type(8))) short bf16x8;   // 8 bf16 = 4 VGPR
typedef __attribute__((ext_vector_type(4))) float f32x4;    // MFMA C/D

typedef unsigned short ushort_t;
typedef unsigned int uint_t;

__device__ __forceinline__ ushort_t f2bfh(float f) {
  __hip_bfloat16 h = __float2bfloat16(f);            // RNE, hw cvt
  return *reinterpret_cast<ushort_t*>(&h);
}
__device__ __forceinline__ float bf2f(ushort_t s) {
  union { uint_t u; float f; } v; v.u = ((uint_t)s) << 16;
  return v.f;
}
__device__ __forceinline__ bf16x8 ldfrag(const ushort_t* p) {
  return *reinterpret_cast<const bf16x8*>(p);
}
__device__ __forceinline__ bf16x8 pack8(float4 a, float4 b) {
  union { bf16x8 v; __hip_bfloat162 h[4]; } u;       // v_cvt_pk_bf16_f32 x4
  u.h[0] = __float22bfloat162_rn(float2{a.x, a.y});
  u.h[1] = __float22bfloat162_rn(float2{a.z, a.w});
  u.h[2] = __float22bfloat162_rn(float2{b.x, b.y});
  u.h[3] = __float22bfloat162_rn(float2{b.z, b.w});
  return u.v;
}

// ---------------------------------------------------------------------------
// Pack weights (fp32 row-major [K][Ncols]) into bf16 MFMA-B fragment order:
//   p[((nt*KT + kt)*64 + lane)*8 + j] = W[kt*32 + (lane>>4)*8 + j][nt*16 + (lane&15)]
// ---------------------------------------------------------------------------
__global__ void pack_weights(const float* __restrict__ Wf,
                             const float* __restrict__ W1,
                             const float* __restrict__ W2,
                             ushort_t* __restrict__ p1,
                             ushort_t* __restrict__ pW1,
                             ushort_t* __restrict__ pW2) {
  int u = blockIdx.x * 256 + threadIdx.x;
  if (u < 32768) {
    int lane = u & 63, rest = u >> 6;
    int kt = rest & 15;
    int kb = kt * 32 + (lane >> 4) * 8;
    int col = (rest >> 4) * 16 + (lane & 15);
#pragma unroll
    for (int j = 0; j < 8; ++j)
      p1[(size_t)u * 8 + j] = f2bfh(Wf[(size_t)(kb + j) * 512 + col]);
  } else if (u < 40960) {
    int v = u - 32768;
    int lane = v & 63;
    int kt = (v >> 6) & 7;
    int kb = kt * 32 + (lane >> 4) * 8;
    int col = (v >> 9) * 16 + (lane & 15);
#pragma unroll
    for (int j = 0; j < 8; ++j)
      pW1[(size_t)v * 8 + j] = f2bfh(W1[(size_t)(kb + j) * 256 + col]);
  } else if (u < 49152) {
    int v = u - 40960;
    int lane = v & 63;
    int kt = (v >> 6) & 7;
    int kb = kt * 32 + (lane >> 4) * 8;
    int col = (v >> 9) * 16 + (lane & 15);
#pragma unroll
    for (int j = 0; j < 8; ++j)
      pW2[(size_t)v * 8 + j] = f2bfh(W2[(size_t)(kb + j) * 256 + col]);
  }
}

// ---------------------------------------------------------------------------
// Fused: 1024 blocks x 64 rows, 8 waves (512 thr).
// LDS 64KB [64][512] bf16 (1KB/row), XOR swz byte ^= (row&15)<<4:
//   phase 1: cond (full K)
//   phase 2: gb bf16 (gamma cols 0-255, beta cols 256-511)
//   phase 3: r1 over gamma-half (stride 1KB), r2 over beta-half
//   phase 4: fp32 out tile [32][256] per half in lds[0,32K)
// GEMM1: wave w owns gb cols [w*64,+64) -> acc[4][4]. GEMM2/3: wave w owns
// H-cols [w*32,+32) -> acc[4][2]. XCD swizzle: rb = (bid%8)*128 + bid/8.
// ---------------------------------------------------------------------------
__global__ __launch_bounds__(512, 2)
void film_fused(const float* __restrict__ x, const float* __restrict__ cond,
                const float* __restrict__ b_film, const float* __restrict__ b1,
                const float* __restrict__ b2,
                const ushort_t* __restrict__ p1, const ushort_t* __restrict__ pW1,
                const ushort_t* __restrict__ pW2, float* __restrict__ out) {
  __shared__ __align__(16) char lds[65536];
  // XCD-aware bijective swizzle (1024 blocks, 8 XCDs, 128 blocks/XCD chunk)
  const int bid = blockIdx.x;
  const int rb = (bid & 7) * 128 + (bid >> 3);
  const int r0 = rb * 64;
  const int t = threadIdx.x;
  const int w = t >> 6;
  const int l = t & 63;
  const int l15 = l & 15;
  const int lhi = l >> 4;

  // bias preloads: GEMM1 dump cols (w*64..+64 of gb), GEMM2/3 cols (w*32..)
  float bfv[4], b1v[2], b2v[2];
#pragma unroll
  for (int tt = 0; tt < 4; ++tt) bfv[tt] = b_film[w * 64 + tt * 16 + l15];
#pragma unroll
  for (int tt = 0; tt < 2; ++tt) {
    int col = w * 32 + tt * 16 + l15;
    b1v[tt] = b1[col];
    b2v[tt] = b2[col];
  }

  // ---- stage cond full-K -> bf16 LDS [64][512] swz
#pragma unroll
  for (int it = 0; it < 8; ++it) {
    int u = it * 512 + t;
    int row = u >> 6, k8 = u & 63;
    const float4* cs = reinterpret_cast<const float4*>(cond + (size_t)(r0 + row) * 512 + k8 * 8);
    float4 a = cs[0], b = cs[1];
    int byte = row * 1024 + k8 * 16;
    byte ^= ((row & 15) << 4);
    *reinterpret_cast<bf16x8*>(lds + byte) = pack8(a, b);
  }
  // GEMM1 B preload kt=0 (4 panels: nt = w*4+tt covers all 32 gb n-tiles)
  bf16x8 bb[2][4];
#pragma unroll
  for (int tt = 0; tt < 4; ++tt)
    bb[0][tt] = ldfrag(p1 + ((size_t)((w * 4 + tt) * 16 + 0) * 64 + l) * 8);
  __syncthreads();   // B1: cond staged

  // ---- GEMM1: acc[4][4] over 16 kt, 2-slot B pipeline
  f32x4 acc[4][4];
#pragma unroll
  for (int m = 0; m < 4; ++m)
#pragma unroll
    for (int n = 0; n < 4; ++n) acc[m][n] = (f32x4){0.f, 0.f, 0.f, 0.f};

#pragma unroll
  for (int kt = 0; kt < 16; ++kt) {
    const int cur = kt & 1;
    if (kt < 15) {
#pragma unroll
      for (int tt = 0; tt < 4; ++tt)
        bb[cur ^ 1][tt] = ldfrag(p1 + ((size_t)((w * 4 + tt) * 16 + kt + 1) * 64 + l) * 8);
    }
    bf16x8 afr[4];
#pragma unroll
    for (int m = 0; m < 4; ++m) {
      int row = m * 16 + l15;
      int byte = row * 1024 + kt * 64 + lhi * 16;
      byte ^= ((row & 15) << 4);
      afr[m] = *reinterpret_cast<const bf16x8*>(lds + byte);
    }
#pragma unroll
    for (int tt = 0; tt < 4; ++tt)
#pragma unroll
      for (int m = 0; m < 4; ++m)
        acc[m][tt] = __builtin_amdgcn_mfma_f32_16x16x32_bf16(afr[m], bb[cur][tt], acc[m][tt], 0, 0, 0);
  }
  __syncthreads();   // B2: all cond reads done -> LDS reusable

  // ---- dump gb(+b_film) bf16 -> LDS [64][512] (wave w covers cols w*64..+64)
#pragma unroll
  for (int tt = 0; tt < 4; ++tt) {
    int col = w * 64 + tt * 16 + l15;
#pragma unroll
    for (int m = 0; m < 4; ++m) {
#pragma unroll
      for (int reg = 0; reg < 4; ++reg) {
        int row = m * 16 + lhi * 4 + reg;
        int byte = row * 1024 + col * 2;
        byte ^= ((row & 15) << 4);
        *reinterpret_cast<ushort_t*>(lds + byte) = f2bfh(acc[m][tt][reg] + bfv[tt]);
      }
    }
  }
  // GEMM2 B preload before the barrier
  bf16x8 bb2[2][2];
#pragma unroll
  for (int tt = 0; tt < 2; ++tt)
    bb2[0][tt] = ldfrag(pW1 + ((size_t)((w * 2 + tt) * 8 + 0) * 64 + l) * 8);
  __syncthreads();   // B3: gb ready

  // ---- FiLM row-major: r1 = relu(gamma*x + beta) IN PLACE over gamma half
#pragma unroll
  for (int i = 0; i < 4; ++i) {
    int u = i * 512 + t;
    int row = u >> 5, c8 = u & 31;        // [64 rows][32 units of 8 gamma-cols]
    int gbyte = row * 1024 + c8 * 16;
    gbyte ^= ((row & 15) << 4);
    int bbyte = row * 1024 + 512 + c8 * 16;
    bbyte ^= ((row & 15) << 4);
    union { bf16x8 v; ushort_t s[8]; } g, be, r;
    g.v = *reinterpret_cast<const bf16x8*>(lds + gbyte);
    be.v = *reinterpret_cast<const bf16x8*>(lds + bbyte);
    const float4* xs = reinterpret_cast<const float4*>(x + (size_t)(r0 + row) * 256 + c8 * 8);
    float4 xa = xs[0], xb = xs[1];
    float xv[8] = {xa.x, xa.y, xa.z, xa.w, xb.x, xb.y, xb.z, xb.w};
#pragma unroll
    for (int j = 0; j < 8; ++j)
      r.s[j] = f2bfh(fmaxf(bf2f(g.s[j]) * xv[j] + bf2f(be.s[j]), 0.f));
    *reinterpret_cast<bf16x8*>(lds + gbyte) = r.v;
  }
  __syncthreads();   // B4: r1 ready (gamma half)

  // ---- GEMM2: acc2 = r1 @ W1 (K=256, 8 kt; A stride 1KB, gamma half)
  f32x4 acc2[4][2];
#pragma unroll
  for (int m = 0; m < 4; ++m)
#pragma unroll
    for (int n = 0; n < 2; ++n) acc2[m][n] = (f32x4){0.f, 0.f, 0.f, 0.f};

#pragma unroll
  for (int kt = 0; kt < 8; ++kt) {
    const int cur = kt & 1;
    if (kt < 7) {
#pragma unroll
      for (int tt = 0; tt < 2; ++tt)
        bb2[cur ^ 1][tt] = ldfrag(pW1 + ((size_t)((w * 2 + tt) * 8 + kt + 1) * 64 + l) * 8);
    }
    bf16x8 afr[4];
#pragma unroll
    for (int m = 0; m < 4; ++m) {
      int row = m * 16 + l15;
      int byte = row * 1024 + kt * 64 + lhi * 16;
      byte ^= ((row & 15) << 4);
      afr[m] = *reinterpret_cast<const bf16x8*>(lds + byte);
    }
#pragma unroll
    for (int tt = 0; tt < 2; ++tt)
#pragma unroll
      for (int m = 0; m < 4; ++m)
        acc2[m][tt] = __builtin_amdgcn_mfma_f32_16x16x32_bf16(afr[m], bb2[cur][tt], acc2[m][tt], 0, 0, 0);
  }

  // ---- r2 = relu(acc2+b1) -> BETA half (disjoint from GEMM2's gamma-half
  // reads -> no barrier needed before these writes). GEMM3 B preload too.
  bf16x8 bb3[2][2];
#pragma unroll
  for (int tt = 0; tt < 2; ++tt)
    bb3[0][tt] = ldfrag(pW2 + ((size_t)((w * 2 + tt) * 8 + 0) * 64 + l) * 8);
#pragma unroll
  for (int tt = 0; tt < 2; ++tt) {
    int col = w * 32 + tt * 16 + l15;
#pragma unroll
    for (int m = 0; m < 4; ++m) {
#pragma unroll
      for (int reg = 0; reg < 4; ++reg) {
        int row = m * 16 + lhi * 4 + reg;
        int byte = row * 1024 + 512 + col * 2;
        byte ^= ((row & 15) << 4);
        *reinterpret_cast<ushort_t*>(lds + byte) = f2bfh(fmaxf(acc2[m][tt][reg] + b1v[tt], 0.f));
      }
    }
  }
  __syncthreads();   // B5: r2 ready (beta half)

  // ---- GEMM3: acc3 = r2 @ W2 (A stride 1KB, beta half)
  f32x4 acc3[4][2];
#pragma unroll
  for (int m = 0; m < 4; ++m)
#pragma unroll
    for (int n = 0; n < 2; ++n) acc3[m][n] = (f32x4){0.f, 0.f, 0.f, 0.f};

#pragma unroll
  for (int kt = 0; kt < 8; ++kt) {
    const int cur = kt & 1;
    if (kt < 7) {
#pragma unroll
      for (int tt = 0; tt < 2; ++tt)
        bb3[cur ^ 1][tt] = ldfrag(pW2 + ((size_t)((w * 2 + tt) * 8 + kt + 1) * 64 + l) * 8);
    }
    bf16x8 afr[4];
#pragma unroll
    for (int m = 0; m < 4; ++m) {
      int row = m * 16 + l15;
      int byte = row * 1024 + 512 + kt * 64 + lhi * 16;
      byte ^= ((row & 15) << 4);
      afr[m] = *reinterpret_cast<const bf16x8*>(lds + byte);
    }
#pragma unroll
    for (int tt = 0; tt < 2; ++tt)
#pragma unroll
      for (int m = 0; m < 4; ++m)
        acc3[m][tt] = __builtin_amdgcn_mfma_f32_16x16x32_bf16(afr[m], bb3[cur][tt], acc3[m][tt], 0, 0, 0);
  }
  __syncthreads();   // B6: all r2 reads done -> whole LDS free

  // ---- epilogue: two 32-row halves through lds[0,32K) (fp32 [32][256] swz),
  // +b2 at dump, +x (L3-warm re-read) at coalesced nontemporal store.
#pragma unroll
  for (int hh = 0; hh < 2; ++hh) {
    if (hh) __syncthreads();   // half-0 store reads done
#pragma unroll
    for (int tt = 0; tt < 2; ++tt) {
      int col = w * 32 + tt * 16 + l15;
#pragma unroll
      for (int mm = 0; mm < 2; ++mm) {
        int m = hh * 2 + mm;
#pragma unroll
        for (int reg = 0; reg < 4; ++reg) {
          int r = mm * 16 + lhi * 4 + reg;
          int byte = r * 1024 + col * 4;
          byte ^= ((r & 15) << 4);
          *reinterpret_cast<float*>(lds + byte) = acc3[m][tt][reg] + b2v[tt];
        }
      }
    }
    __syncthreads();
#pragma unroll
    for (int i = 0; i < 4; ++i) {
      int u = i * 512 + t;
      int r = u >> 6, c4 = u & 63;   // [32 rows][64 units of 4 cols]
      int byte = r * 1024 + c4 * 16;
      byte ^= ((r & 15) << 4);
      f32x4 v = *reinterpret_cast<const f32x4*>(lds + byte);
      int grow = hh * 32 + r;
      const float4 xres = *reinterpret_cast<const float4*>(
          x + (size_t)(r0 + grow) * 256 + c4 * 4);
      v.x += xres.x; v.y += xres.y; v.z += xres.z; v.w += xres.w;
      f32x4* op = reinterpret_cast<f32x4*>(out + (size_t)(r0 + grow) * 256 + c4 * 4);
      __builtin_nontemporal_store(v, op);
    }
  }
}

extern "C" void kernel_launch(void* const* d_in, const int* in_sizes, int n_in,
                              void* d_out, int out_size, void* d_ws, size_t ws_size,
                              hipStream_t stream) {
  const float* x      = (const float*)d_in[0];
  const float* cond   = (const float*)d_in[1];
  const float* W_film = (const float*)d_in[2];
  const float* b_film = (const float*)d_in[3];
  const float* W1     = (const float*)d_in[4];
  const float* b1     = (const float*)d_in[5];
  const float* W2     = (const float*)d_in[6];
  const float* b2     = (const float*)d_in[7];
  float* out = (float*)d_out;

  ushort_t* p1  = (ushort_t*)d_ws;       // 512KB
  ushort_t* pW1 = p1 + 262144;           // 128KB
  ushort_t* pW2 = pW1 + 65536;           // 128KB

  hipLaunchKernelGGL(pack_weights, dim3(192), dim3(256), 0, stream,
                     W_film, W1, W2, p1, pW1, pW2);
  hipLaunchKernelGGL(film_fused, dim3(1024), dim3(512), 0, stream,
                     x, cond, b_film, b1, b2, p1, pW1, pW2, out);
}

// Round 25
// 100.700 us; speedup vs baseline: 4.7908x; 1.0770x over previous
//
#include <hip/hip_runtime.h>
#include <hip/hip_bf16.h>

// FiLM + 2-layer preact resnet. N=65536, H=256, C=512.
// Round 25: EXACT restore of round 18 — the best-measured kernel (98.3us,
// VGPR 112, zero spill). r24's two tweaks (setprio removal, XCD swizzle)
// both regressed (108.5us); r14-r23 tested micro-pipelining, TLP, DMA
// staging, kernel-split and cross-tile overlap — all null or negative.
// This fused structure (gamma/beta exchanged through LDS, in-place r1/r2,
// fp32-LDS epilogue, L3-warm x residual) is the session's optimum.

typedef __attribute__((ext_vector_type(8))) short bf16x8;   // 8 bf16 = 4 VGPR
typedef __attribute__((ext_vector_type(4))) float f32x4;    // MFMA C/D

typedef unsigned short ushort_t;
typedef unsigned int uint_t;

__device__ __forceinline__ ushort_t f2bfh(float f) {
  __hip_bfloat16 h = __float2bfloat16(f);            // RNE, hw cvt
  return *reinterpret_cast<ushort_t*>(&h);
}
__device__ __forceinline__ float bf2f(ushort_t s) {
  union { uint_t u; float f; } v; v.u = ((uint_t)s) << 16;
  return v.f;
}
__device__ __forceinline__ bf16x8 ldfrag(const ushort_t* p) {
  return *reinterpret_cast<const bf16x8*>(p);
}
__device__ __forceinline__ bf16x8 pack8(float4 a, float4 b) {
  union { bf16x8 v; __hip_bfloat162 h[4]; } u;       // v_cvt_pk_bf16_f32 x4
  u.h[0] = __float22bfloat162_rn(float2{a.x, a.y});
  u.h[1] = __float22bfloat162_rn(float2{a.z, a.w});
  u.h[2] = __float22bfloat162_rn(float2{b.x, b.y});
  u.h[3] = __float22bfloat162_rn(float2{b.z, b.w});
  return u.v;
}

// ---------------------------------------------------------------------------
// Pack weights (fp32 row-major [K][Ncols]) into bf16 MFMA-B fragment order:
//   p[((nt*KT + kt)*64 + lane)*8 + j] = W[kt*32 + (lane>>4)*8 + j][nt*16 + (lane&15)]
// ---------------------------------------------------------------------------
__global__ void pack_weights(const float* __restrict__ Wf,
                             const float* __restrict__ W1,
                             const float* __restrict__ W2,
                             ushort_t* __restrict__ p1,
                             ushort_t* __restrict__ pW1,
                             ushort_t* __restrict__ pW2) {
  int u = blockIdx.x * 256 + threadIdx.x;
  if (u < 32768) {
    int lane = u & 63, rest = u >> 6;
    int kt = rest & 15;
    int kb = kt * 32 + (lane >> 4) * 8;
    int col = (rest >> 4) * 16 + (lane & 15);
#pragma unroll
    for (int j = 0; j < 8; ++j)
      p1[(size_t)u * 8 + j] = f2bfh(Wf[(size_t)(kb + j) * 512 + col]);
  } else if (u < 40960) {
    int v = u - 32768;
    int lane = v & 63;
    int kt = (v >> 6) & 7;
    int kb = kt * 32 + (lane >> 4) * 8;
    int col = (v >> 9) * 16 + (lane & 15);
#pragma unroll
    for (int j = 0; j < 8; ++j)
      pW1[(size_t)v * 8 + j] = f2bfh(W1[(size_t)(kb + j) * 256 + col]);
  } else if (u < 49152) {
    int v = u - 40960;
    int lane = v & 63;
    int kt = (v >> 6) & 7;
    int kb = kt * 32 + (lane >> 4) * 8;
    int col = (v >> 9) * 16 + (lane & 15);
#pragma unroll
    for (int j = 0; j < 8; ++j)
      pW2[(size_t)v * 8 + j] = f2bfh(W2[(size_t)(kb + j) * 256 + col]);
  }
}

// ---------------------------------------------------------------------------
// Fused: 1024 blocks x 64 rows, 8 waves (512 thr).
// LDS 64KB [64][512] bf16 (1KB/row), XOR swz byte ^= (row&15)<<4:
//   phase 1: cond (full K)
//   phase 2: gb bf16 (gamma cols 0-255, beta cols 256-511)
//   phase 3: r1 over gamma-half (stride 1KB), r2 over beta-half
//   phase 4: fp32 out tile [32][256] per half in lds[0,32K)
// GEMM1: wave w owns gb cols [w*64,+64) -> acc[4][4]. GEMM2/3: wave w owns
// H-cols [w*32,+32) -> acc[4][2].
// ---------------------------------------------------------------------------
__global__ __launch_bounds__(512, 2)
void film_fused(const float* __restrict__ x, const float* __restrict__ cond,
                const float* __restrict__ b_film, const float* __restrict__ b1,
                const float* __restrict__ b2,
                const ushort_t* __restrict__ p1, const ushort_t* __restrict__ pW1,
                const ushort_t* __restrict__ pW2, float* __restrict__ out) {
  __shared__ __align__(16) char lds[65536];
  const int r0 = blockIdx.x * 64;
  const int t = threadIdx.x;
  const int w = t >> 6;
  const int l = t & 63;
  const int l15 = l & 15;
  const int lhi = l >> 4;

  // bias preloads: GEMM1 dump cols (w*64..+64 of gb), GEMM2/3 cols (w*32..)
  float bfv[4], b1v[2], b2v[2];
#pragma unroll
  for (int tt = 0; tt < 4; ++tt) bfv[tt] = b_film[w * 64 + tt * 16 + l15];
#pragma unroll
  for (int tt = 0; tt < 2; ++tt) {
    int col = w * 32 + tt * 16 + l15;
    b1v[tt] = b1[col];
    b2v[tt] = b2[col];
  }

  // ---- stage cond full-K -> bf16 LDS [64][512] swz
#pragma unroll
  for (int it = 0; it < 8; ++it) {
    int u = it * 512 + t;
    int row = u >> 6, k8 = u & 63;
    const float4* cs = reinterpret_cast<const float4*>(cond + (size_t)(r0 + row) * 512 + k8 * 8);
    float4 a = cs[0], b = cs[1];
    int byte = row * 1024 + k8 * 16;
    byte ^= ((row & 15) << 4);
    *reinterpret_cast<bf16x8*>(lds + byte) = pack8(a, b);
  }
  // GEMM1 B preload kt=0 (4 panels: nt = w*4+tt covers all 32 gb n-tiles)
  bf16x8 bb[2][4];
#pragma unroll
  for (int tt = 0; tt < 4; ++tt)
    bb[0][tt] = ldfrag(p1 + ((size_t)((w * 4 + tt) * 16 + 0) * 64 + l) * 8);
  __syncthreads();   // B1: cond staged

  // ---- GEMM1: acc[4][4] over 16 kt, 2-slot B pipeline
  f32x4 acc[4][4];
#pragma unroll
  for (int m = 0; m < 4; ++m)
#pragma unroll
    for (int n = 0; n < 4; ++n) acc[m][n] = (f32x4){0.f, 0.f, 0.f, 0.f};

#pragma unroll
  for (int kt = 0; kt < 16; ++kt) {
    const int cur = kt & 1;
    if (kt < 15) {
#pragma unroll
      for (int tt = 0; tt < 4; ++tt)
        bb[cur ^ 1][tt] = ldfrag(p1 + ((size_t)((w * 4 + tt) * 16 + kt + 1) * 64 + l) * 8);
    }
    bf16x8 afr[4];
#pragma unroll
    for (int m = 0; m < 4; ++m) {
      int row = m * 16 + l15;
      int byte = row * 1024 + kt * 64 + lhi * 16;
      byte ^= ((row & 15) << 4);
      afr[m] = *reinterpret_cast<const bf16x8*>(lds + byte);
    }
    __builtin_amdgcn_s_setprio(1);
#pragma unroll
    for (int tt = 0; tt < 4; ++tt)
#pragma unroll
      for (int m = 0; m < 4; ++m)
        acc[m][tt] = __builtin_amdgcn_mfma_f32_16x16x32_bf16(afr[m], bb[cur][tt], acc[m][tt], 0, 0, 0);
    __builtin_amdgcn_s_setprio(0);
  }
  __syncthreads();   // B2: all cond reads done -> LDS reusable

  // ---- dump gb(+b_film) bf16 -> LDS [64][512] (wave w covers cols w*64..+64)
#pragma unroll
  for (int tt = 0; tt < 4; ++tt) {
    int col = w * 64 + tt * 16 + l15;
#pragma unroll
    for (int m = 0; m < 4; ++m) {
#pragma unroll
      for (int reg = 0; reg < 4; ++reg) {
        int row = m * 16 + lhi * 4 + reg;
        int byte = row * 1024 + col * 2;
        byte ^= ((row & 15) << 4);
        *reinterpret_cast<ushort_t*>(lds + byte) = f2bfh(acc[m][tt][reg] + bfv[tt]);
      }
    }
  }
  // GEMM2 B preload before the barrier
  bf16x8 bb2[2][2];
#pragma unroll
  for (int tt = 0; tt < 2; ++tt)
    bb2[0][tt] = ldfrag(pW1 + ((size_t)((w * 2 + tt) * 8 + 0) * 64 + l) * 8);
  __syncthreads();   // B3: gb ready

  // ---- FiLM row-major: r1 = relu(gamma*x + beta) written IN PLACE over the
  // gamma half. Each (row, 8-col unit) slot read+written by exactly one thread.
#pragma unroll
  for (int i = 0; i < 4; ++i) {
    int u = i * 512 + t;
    int row = u >> 5, c8 = u & 31;        // [64 rows][32 units of 8 gamma-cols]
    int gbyte = row * 1024 + c8 * 16;
    gbyte ^= ((row & 15) << 4);
    int bbyte = row * 1024 + 512 + c8 * 16;
    bbyte ^= ((row & 15) << 4);
    union { bf16x8 v; ushort_t s[8]; } g, be, r;
    g.v = *reinterpret_cast<const bf16x8*>(lds + gbyte);
    be.v = *reinterpret_cast<const bf16x8*>(lds + bbyte);
    const float4* xs = reinterpret_cast<const float4*>(x + (size_t)(r0 + row) * 256 + c8 * 8);
    float4 xa = xs[0], xb = xs[1];
    float xv[8] = {xa.x, xa.y, xa.z, xa.w, xb.x, xb.y, xb.z, xb.w};
#pragma unroll
    for (int j = 0; j < 8; ++j)
      r.s[j] = f2bfh(fmaxf(bf2f(g.s[j]) * xv[j] + bf2f(be.s[j]), 0.f));
    *reinterpret_cast<bf16x8*>(lds + gbyte) = r.v;
  }
  __syncthreads();   // B4: r1 ready (gamma half)

  // ---- GEMM2: acc2 = r1 @ W1 (K=256, 8 kt; A stride 1KB, gamma half)
  f32x4 acc2[4][2];
#pragma unroll
  for (int m = 0; m < 4; ++m)
#pragma unroll
    for (int n = 0; n < 2; ++n) acc2[m][n] = (f32x4){0.f, 0.f, 0.f, 0.f};

#pragma unroll
  for (int kt = 0; kt < 8; ++kt) {
    const int cur = kt & 1;
    if (kt < 7) {
#pragma unroll
      for (int tt = 0; tt < 2; ++tt)
        bb2[cur ^ 1][tt] = ldfrag(pW1 + ((size_t)((w * 2 + tt) * 8 + kt + 1) * 64 + l) * 8);
    }
    bf16x8 afr[4];
#pragma unroll
    for (int m = 0; m < 4; ++m) {
      int row = m * 16 + l15;
      int byte = row * 1024 + kt * 64 + lhi * 16;
      byte ^= ((row & 15) << 4);
      afr[m] = *reinterpret_cast<const bf16x8*>(lds + byte);
    }
    __builtin_amdgcn_s_setprio(1);
#pragma unroll
    for (int tt = 0; tt < 2; ++tt)
#pragma unroll
      for (int m = 0; m < 4; ++m)
        acc2[m][tt] = __builtin_amdgcn_mfma_f32_16x16x32_bf16(afr[m], bb2[cur][tt], acc2[m][tt], 0, 0, 0);
    __builtin_amdgcn_s_setprio(0);
  }

  // ---- r2 = relu(acc2+b1) -> BETA half (disjoint from GEMM2's gamma-half
  // reads -> no barrier needed before these writes). GEMM3 B preload too.
  bf16x8 bb3[2][2];
#pragma unroll
  for (int tt = 0; tt < 2; ++tt)
    bb3[0][tt] = ldfrag(pW2 + ((size_t)((w * 2 + tt) * 8 + 0) * 64 + l) * 8);
#pragma unroll
  for (int tt = 0; tt < 2; ++tt) {
    int col = w * 32 + tt * 16 + l15;
#pragma unroll
    for (int m = 0; m < 4; ++m) {
#pragma unroll
      for (int reg = 0; reg < 4; ++reg) {
        int row = m * 16 + lhi * 4 + reg;
        int byte = row * 1024 + 512 + col * 2;
        byte ^= ((row & 15) << 4);
        *reinterpret_cast<ushort_t*>(lds + byte) = f2bfh(fmaxf(acc2[m][tt][reg] + b1v[tt], 0.f));
      }
    }
  }
  __syncthreads();   // B5: r2 ready (beta half)

  // ---- GEMM3: acc3 = r2 @ W2 (A stride 1KB, beta half)
  f32x4 acc3[4][2];
#pragma unroll
  for (int m = 0; m < 4; ++m)
#pragma unroll
    for (int n = 0; n < 2; ++n) acc3[m][n] = (f32x4){0.f, 0.f, 0.f, 0.f};

#pragma unroll
  for (int kt = 0; kt < 8; ++kt) {
    const int cur = kt & 1;
    if (kt < 7) {
#pragma unroll
      for (int tt = 0; tt < 2; ++tt)
        bb3[cur ^ 1][tt] = ldfrag(pW2 + ((size_t)((w * 2 + tt) * 8 + kt + 1) * 64 + l) * 8);
    }
    bf16x8 afr[4];
#pragma unroll
    for (int m = 0; m < 4; ++m) {
      int row = m * 16 + l15;
      int byte = row * 1024 + 512 + kt * 64 + lhi * 16;
      byte ^= ((row & 15) << 4);
      afr[m] = *reinterpret_cast<const bf16x8*>(lds + byte);
    }
    __builtin_amdgcn_s_setprio(1);
#pragma unroll
    for (int tt = 0; tt < 2; ++tt)
#pragma unroll
      for (int m = 0; m < 4; ++m)
        acc3[m][tt] = __builtin_amdgcn_mfma_f32_16x16x32_bf16(afr[m], bb3[cur][tt], acc3[m][tt], 0, 0, 0);
    __builtin_amdgcn_s_setprio(0);
  }
  __syncthreads();   // B6: all r2 reads done -> whole LDS free

  // ---- epilogue: two 32-row halves through lds[0,32K) (fp32 [32][256] swz),
  // +b2 at dump, +x (L3-warm re-read) at coalesced nontemporal store.
#pragma unroll
  for (int hh = 0; hh < 2; ++hh) {
    if (hh) __syncthreads();   // half-0 store reads done
#pragma unroll
    for (int tt = 0; tt < 2; ++tt) {
      int col = w * 32 + tt * 16 + l15;
#pragma unroll
      for (int mm = 0; mm < 2; ++mm) {
        int m = hh * 2 + mm;
#pragma unroll
        for (int reg = 0; reg < 4; ++reg) {
          int r = mm * 16 + lhi * 4 + reg;
          int byte = r * 1024 + col * 4;
          byte ^= ((r & 15) << 4);
          *reinterpret_cast<float*>(lds + byte) = acc3[m][tt][reg] + b2v[tt];
        }
      }
    }
    __syncthreads();
#pragma unroll
    for (int i = 0; i < 4; ++i) {
      int u = i * 512 + t;
      int r = u >> 6, c4 = u & 63;   // [32 rows][64 units of 4 cols]
      int byte = r * 1024 + c4 * 16;
      byte ^= ((r & 15) << 4);
      f32x4 v = *reinterpret_cast<const f32x4*>(lds + byte);
      int grow = hh * 32 + r;
      const float4 xres = *reinterpret_cast<const float4*>(
          x + (size_t)(r0 + grow) * 256 + c4 * 4);
      v.x += xres.x; v.y += xres.y; v.z += xres.z; v.w += xres.w;
      f32x4* op = reinterpret_cast<f32x4*>(out + (size_t)(r0 + grow) * 256 + c4 * 4);
      __builtin_nontemporal_store(v, op);
    }
  }
}

extern "C" void kernel_launch(void* const* d_in, const int* in_sizes, int n_in,
                              void* d_out, int out_size, void* d_ws, size_t ws_size,
                              hipStream_t stream) {
  const float* x      = (const float*)d_in[0];
  const float* cond   = (const float*)d_in[1];
  const float* W_film = (const float*)d_in[2];
  const float* b_film = (const float*)d_in[3];
  const float* W1     = (const float*)d_in[4];
  const float* b1     = (const float*)d_in[5];
  const float* W2     = (const float*)d_in[6];
  const float* b2     = (const float*)d_in[7];
  float* out = (float*)d_out;

  ushort_t* p1  = (ushort_t*)d_ws;       // 512KB
  ushort_t* pW1 = p1 + 262144;           // 128KB
  ushort_t* pW2 = pW1 + 65536;           // 128KB

  hipLaunchKernelGGL(pack_weights, dim3(192), dim3(256), 0, stream,
                     W_film, W1, W2, p1, pW1, pW2);
  hipLaunchKernelGGL(film_fused, dim3(1024), dim3(512), 0, stream,
                     x, cond, b_film, b1, b2, p1, pW1, pW2, out);
}